// Round 4
// baseline (310.911 us; speedup 1.0000x reference)
//
#include <hip/hip_runtime.h>
#include <hip/hip_bf16.h>
#include <math.h>

#define B_ 32
#define H_ 1024
#define S_ 1024

typedef float  f32x4_t  __attribute__((ext_vector_type(4)));
typedef float  f32x16_t __attribute__((ext_vector_type(16)));
typedef long long i64;
typedef i64 i64x2 __attribute__((ext_vector_type(2)));
typedef unsigned char u8;

// tanh via hw exp2 + rcp (~5 VALU inst, ~1e-6 abs err; saturates correctly)
__device__ __forceinline__ float tanh_fast(float x) {
    float e = __builtin_amdgcn_exp2f(x * 2.885390081777927f);  // e^(2x)
    return 1.f - 2.f * __builtin_amdgcn_rcpf(e + 1.f);
}

// fp8 k-permutation within a 32-k group: swap bits 3<->4 (involution).
__device__ __forceinline__ int kperm(int k) {
    return (k & ~24) | ((k & 8) << 1) | ((k & 16) >> 1);
}

// ---------------------------------------------------------------------------
// prep_kernel (round-12): one dispatch, 3 roles.
//
//  Role 0 [0,1024): enc f32 -> encF8 e4m3, kt-tiled (byte p of a 32B chunk =
//    source row kperm(p)). ROW-STREAMING remap: block = (b, kt) reads its 32
//    rows COMPLETELY (128 KB contiguous slab). Thread t owns cols 4t..4t+3;
//    for a fixed row-index i the wave's 64 lanes read 1 KB CONTIGUOUS from a
//    single row, and the block's 4 waves tile the full 4 KB row. Rounds
//    0/1/3 all read 256-512B fragments of rows 4KB apart (partial DRAM-page
//    consumption) and all pinned at ~2.1 TB/s regardless of load width /
//    MLP depth (r0 counters: occ 59%, VALU 4%, HBM 17% -- every pipe idle
//    => memory-system pattern limit, not issue limit). Full-row consumption
//    is the fix. Output bytes bit-identical to previous rounds.
//  Role 1 [1024,2048): W2f8[kt][h][32B] = e4m3(64 * W[h][H+k]) + zero
//    logits/ctx.
//  Role 2 [2048,2304): t1[b,h] = bias[h] + sum_k hidden[b,k]*W[h,k].
// ---------------------------------------------------------------------------
__global__ __launch_bounds__(256) void prep_kernel(
    const float* __restrict__ enc, const float* __restrict__ W,
    const float* __restrict__ hidden, const float* __restrict__ bias,
    u8* __restrict__ encF8, u8* __restrict__ W2f8,
    float* __restrict__ t1, float* __restrict__ logits,
    float* __restrict__ ctx)
{
    const int idx = blockIdx.x;
    const int tid = threadIdx.x;
    if (idx < 1024) {
        const int b  = idx >> 5;            // 0..31
        const int kt = idx & 31;            // 0..31
        const float* rowbase = enc + ((size_t)b * S_ + (size_t)kt * 32) * H_;
        u8* obase = encF8 + (size_t)b * 1048576 + (size_t)kt * 32768
                  + (size_t)tid * 4 * 32;   // cols 4t..4t+3, stride 32B each

        #pragma unroll
        for (int c = 0; c < 2; ++c) {       // khalf: bytes [c*16, c*16+16)
            f32x4_t f[16];
            #pragma unroll
            for (int i = 0; i < 16; ++i)
                f[i] = *reinterpret_cast<const f32x4_t*>(
                    rowbase + (size_t)kperm(c * 16 + i) * H_ + 4 * tid);
            #pragma unroll
            for (int j = 0; j < 4; ++j) {   // col 4t+j
                int t0;
                int4 wv;
                t0   = __builtin_amdgcn_cvt_pk_fp8_f32(f[0][j],  f[1][j],  0,  false);
                wv.x = __builtin_amdgcn_cvt_pk_fp8_f32(f[2][j],  f[3][j],  t0, true);
                t0   = __builtin_amdgcn_cvt_pk_fp8_f32(f[4][j],  f[5][j],  0,  false);
                wv.y = __builtin_amdgcn_cvt_pk_fp8_f32(f[6][j],  f[7][j],  t0, true);
                t0   = __builtin_amdgcn_cvt_pk_fp8_f32(f[8][j],  f[9][j],  0,  false);
                wv.z = __builtin_amdgcn_cvt_pk_fp8_f32(f[10][j], f[11][j], t0, true);
                t0   = __builtin_amdgcn_cvt_pk_fp8_f32(f[12][j], f[13][j], 0,  false);
                wv.w = __builtin_amdgcn_cvt_pk_fp8_f32(f[14][j], f[15][j], t0, true);
                *reinterpret_cast<int4*>(obase + (size_t)j * 32 + c * 16) = wv;
            }
        }
    } else if (idx < 2048) {
        int h = idx - 1024;  // one h row
        if (tid < 64) {      // zero logits (first 32768) then ctx (next 32768)
            int z = h * 64 + tid;
            if (z < B_ * S_) logits[z] = 0.f;
            else             ctx[z - B_ * S_] = 0.f;
        }
        int kt = tid >> 3;            // 0..31
        int q  = tid & 7;             // dest 4-byte word in 32B chunk
        int src = kperm(q * 4);       // contiguous 4 source floats
        float4 wv = *reinterpret_cast<const float4*>(
            W + (size_t)h * (2 * H_) + H_ + kt * 32 + src);
        int pw = __builtin_amdgcn_cvt_pk_fp8_f32(wv.x * 64.f, wv.y * 64.f, 0, false);
        pw     = __builtin_amdgcn_cvt_pk_fp8_f32(wv.z * 64.f, wv.w * 64.f, pw, true);
        *reinterpret_cast<int*>(W2f8 + (size_t)kt * 32768 + (size_t)h * 32 + q * 4) = pw;
    } else {
        int h    = (idx - 2048) * 4 + (tid >> 6);
        int lane = tid & 63;
        const float4* wp = reinterpret_cast<const float4*>(W + (size_t)h * (2 * H_));
        float4 w0 = wp[lane], w1 = wp[lane + 64], w2 = wp[lane + 128], w3 = wp[lane + 192];
        float bh = bias[h];
        for (int b = 0; b < B_; ++b) {
            const float4* hp = reinterpret_cast<const float4*>(hidden + b * H_);
            float4 h0 = hp[lane], h1 = hp[lane + 64], h2 = hp[lane + 128], h3 = hp[lane + 192];
            float a = w0.x*h0.x + w0.y*h0.y + w0.z*h0.z + w0.w*h0.w
                    + w1.x*h1.x + w1.y*h1.y + w1.z*h1.z + w1.w*h1.w
                    + w2.x*h2.x + w2.y*h2.y + w2.z*h2.z + w2.w*h2.w
                    + w3.x*h3.x + w3.y*h3.y + w3.z*h3.z + w3.w*h3.w;
            #pragma unroll
            for (int off = 1; off < 64; off <<= 1) a += __shfl_xor(a, off);
            if (lane == 0) t1[b * H_ + h] = a + bh;
        }
    }
}

// ---------------------------------------------------------------------------
// Energy GEMM v8 — FLAT (no LDS, no barriers): fragments loaded straight
// global->VGPR. The kt-tiled layouts make a wave's fragment load a fully
// coalesced 1KB segment (64 lanes x 16B at (row)*32 + khalf*16). W2f8 (1MB)
// + XCD-pinned B s-tiles are L2-resident (round-6 verified, FETCH 21MB).
// Depth-1 register prefetch: load kt+1 while computing kt; no syncthreads
// anywhere -> compiler uses fine-grained vmcnt (AITER-style), all waves
// pipeline independently.
//   D[h,s] = sum_k W2[h,k]*enc[b,k,s]; logits[b,s] += sum_h v[h]*tanh(D+t1)
// ---------------------------------------------------------------------------
__global__ __launch_bounds__(256) void energy_kernel(
    const u8* __restrict__ W2f8, const u8* __restrict__ encF8,
    const float* __restrict__ t1, const float* __restrict__ v,
    float* __restrict__ logits)
{
    // XCD decode (round-6): all 8 h-tiles of one (s,b) group share id%8.
    const int id = blockIdx.x;
    const int q  = id >> 3, r = id & 7;
    const int ht = q & 7;
    const int g  = r + ((q >> 3) << 3);
    const int b  = g >> 3;
    const int h0 = ht * 128;
    const int s0 = (g & 7) * 128;

    const int tid   = threadIdx.x;
    const int lane  = tid & 63;
    const int wid   = tid >> 6;
    const int wm    = (wid & 1) * 64;
    const int wn    = (wid >> 1) * 64;
    const int l32   = lane & 31;
    const int khalf = lane >> 5;

    // per-lane fragment stream bases (advance 32768 B per kt)
    const u8* aP = W2f8 + (size_t)(h0 + wm + l32) * 32 + khalf * 16;
    const u8* bP = encF8 + (size_t)b * 1048576
                 + (size_t)(s0 + wn + l32) * 32 + khalf * 16;

    f32x16_t acc[2][2] = {};

    i64x2 ca0 = *reinterpret_cast<const i64x2*>(aP);
    i64x2 ca1 = *reinterpret_cast<const i64x2*>(aP + 1024);
    i64x2 cb0 = *reinterpret_cast<const i64x2*>(bP);
    i64x2 cb1 = *reinterpret_cast<const i64x2*>(bP + 1024);
    const u8* aN = aP + 32768;
    const u8* bN = bP + 32768;

    for (int kt = 0; kt < 31; ++kt) {
        i64x2 na0 = *reinterpret_cast<const i64x2*>(aN);
        i64x2 na1 = *reinterpret_cast<const i64x2*>(aN + 1024);
        i64x2 nb0 = *reinterpret_cast<const i64x2*>(bN);
        i64x2 nb1 = *reinterpret_cast<const i64x2*>(bN + 1024);
        aN += 32768; bN += 32768;

        acc[0][0] = __builtin_amdgcn_mfma_f32_32x32x16_fp8_fp8(ca0.x, cb0.x, acc[0][0], 0, 0, 0);
        acc[0][1] = __builtin_amdgcn_mfma_f32_32x32x16_fp8_fp8(ca0.x, cb1.x, acc[0][1], 0, 0, 0);
        acc[1][0] = __builtin_amdgcn_mfma_f32_32x32x16_fp8_fp8(ca1.x, cb0.x, acc[1][0], 0, 0, 0);
        acc[1][1] = __builtin_amdgcn_mfma_f32_32x32x16_fp8_fp8(ca1.x, cb1.x, acc[1][1], 0, 0, 0);
        acc[0][0] = __builtin_amdgcn_mfma_f32_32x32x16_fp8_fp8(ca0.y, cb0.y, acc[0][0], 0, 0, 0);
        acc[0][1] = __builtin_amdgcn_mfma_f32_32x32x16_fp8_fp8(ca0.y, cb1.y, acc[0][1], 0, 0, 0);
        acc[1][0] = __builtin_amdgcn_mfma_f32_32x32x16_fp8_fp8(ca1.y, cb0.y, acc[1][0], 0, 0, 0);
        acc[1][1] = __builtin_amdgcn_mfma_f32_32x32x16_fp8_fp8(ca1.y, cb1.y, acc[1][1], 0, 0, 0);

        ca0 = na0; ca1 = na1; cb0 = nb0; cb1 = nb1;
    }
    acc[0][0] = __builtin_amdgcn_mfma_f32_32x32x16_fp8_fp8(ca0.x, cb0.x, acc[0][0], 0, 0, 0);
    acc[0][1] = __builtin_amdgcn_mfma_f32_32x32x16_fp8_fp8(ca0.x, cb1.x, acc[0][1], 0, 0, 0);
    acc[1][0] = __builtin_amdgcn_mfma_f32_32x32x16_fp8_fp8(ca1.x, cb0.x, acc[1][0], 0, 0, 0);
    acc[1][1] = __builtin_amdgcn_mfma_f32_32x32x16_fp8_fp8(ca1.x, cb1.x, acc[1][1], 0, 0, 0);
    acc[0][0] = __builtin_amdgcn_mfma_f32_32x32x16_fp8_fp8(ca0.y, cb0.y, acc[0][0], 0, 0, 0);
    acc[0][1] = __builtin_amdgcn_mfma_f32_32x32x16_fp8_fp8(ca0.y, cb1.y, acc[0][1], 0, 0, 0);
    acc[1][0] = __builtin_amdgcn_mfma_f32_32x32x16_fp8_fp8(ca1.y, cb0.y, acc[1][0], 0, 0, 0);
    acc[1][1] = __builtin_amdgcn_mfma_f32_32x32x16_fp8_fp8(ca1.y, cb1.y, acc[1][1], 0, 0, 0);

    // epilogue: 32x32 C/D: col = lane&31, row = (r&3)+8*(r>>2)+4*(lane>>5)
    float pn0 = 0.f, pn1 = 0.f;
    #pragma unroll
    for (int mt = 0; mt < 2; ++mt)
        #pragma unroll
        for (int rr = 0; rr < 16; ++rr) {
            int rowm = wm + mt * 32 + (rr & 3) + 8 * (rr >> 2) + 4 * khalf;
            int h = h0 + rowm;
            float tv = t1[b * H_ + h];
            float vv = v[h];
            pn0 += vv * tanh_fast(acc[mt][0][rr] * 0.015625f + tv);
            pn1 += vv * tanh_fast(acc[mt][1][rr] * 0.015625f + tv);
        }
    pn0 += __shfl_xor(pn0, 32);
    pn1 += __shfl_xor(pn1, 32);
    if (lane < 32) {
        atomicAdd(&logits[(size_t)b * S_ + s0 + wn + l32], pn0);
        atomicAdd(&logits[(size_t)b * S_ + s0 + wn + 32 + l32], pn1);
    }
}

// ---------------------------------------------------------------------------
// Fused softmax + context (round-11): grid (32 s-chunks, B) = 1024 blocks
// = 4 blocks/CU. Redundant softmax into LDS; main loop 32 rows with 16-deep
// independent float4 pipeline (unroll 16); atomicAdd into ctx.
// blockIdx.x==0 writes scores.
// ---------------------------------------------------------------------------
__global__ __launch_bounds__(256) void ctx_kernel(
    const float* __restrict__ enc, const float* __restrict__ logits,
    float* __restrict__ scores, float* __restrict__ ctx)
{
    __shared__ float sc[1024];
    __shared__ float red[8];
    const int b    = blockIdx.y;
    const int s0   = blockIdx.x * 32;
    const int tid  = threadIdx.x;
    const int lane = tid & 63;
    const int w    = tid >> 6;

    float4 lg = *reinterpret_cast<const float4*>(logits + (size_t)b * S_ + tid * 4);
    float mx = fmaxf(fmaxf(lg.x, lg.y), fmaxf(lg.z, lg.w));
    #pragma unroll
    for (int off = 1; off < 64; off <<= 1) mx = fmaxf(mx, __shfl_xor(mx, off));
    if (lane == 0) red[w] = mx;
    __syncthreads();
    mx = fmaxf(fmaxf(red[0], red[1]), fmaxf(red[2], red[3]));
    const float L2E = 1.44269504088896f;
    float e0 = __builtin_amdgcn_exp2f((lg.x - mx) * L2E);
    float e1 = __builtin_amdgcn_exp2f((lg.y - mx) * L2E);
    float e2 = __builtin_amdgcn_exp2f((lg.z - mx) * L2E);
    float e3 = __builtin_amdgcn_exp2f((lg.w - mx) * L2E);
    float s = e0 + e1 + e2 + e3;
    #pragma unroll
    for (int off = 1; off < 64; off <<= 1) s += __shfl_xor(s, off);
    if (lane == 0) red[4 + w] = s;
    __syncthreads();
    float inv = 1.f / (red[4] + red[5] + red[6] + red[7]);
    float4 sv = { e0 * inv, e1 * inv, e2 * inv, e3 * inv };
    *reinterpret_cast<float4*>(&sc[tid * 4]) = sv;
    if (blockIdx.x == 0)
        *reinterpret_cast<float4*>(scores + (size_t)b * S_ + tid * 4) = sv;
    __syncthreads();

    f32x4_t accv = {0.f, 0.f, 0.f, 0.f};
    const float* ebase = enc + ((size_t)b * S_ + s0) * H_ + tid * 4;
    #pragma unroll 16
    for (int si = 0; si < 32; ++si) {
        float wgt = sc[s0 + si];
        float4 ev = *reinterpret_cast<const float4*>(ebase + (size_t)si * H_);
        accv[0] += wgt * ev.x;
        accv[1] += wgt * ev.y;
        accv[2] += wgt * ev.z;
        accv[3] += wgt * ev.w;
    }
    float* cp = ctx + (size_t)b * H_ + tid * 4;
    atomicAdd(cp + 0, accv[0]);
    atomicAdd(cp + 1, accv[1]);
    atomicAdd(cp + 2, accv[2]);
    atomicAdd(cp + 3, accv[3]);
}

// ---------------------------------------------------------------------------
extern "C" void kernel_launch(void* const* d_in, const int* in_sizes, int n_in,
                              void* d_out, int out_size, void* d_ws, size_t ws_size,
                              hipStream_t stream)
{
    (void)in_sizes; (void)n_in; (void)out_size; (void)ws_size;
    const float* hidden = (const float*)d_in[0];
    const float* enc    = (const float*)d_in[1];
    const float* W      = (const float*)d_in[2];
    const float* bias   = (const float*)d_in[3];
    const float* v      = (const float*)d_in[4];

    float* out    = (float*)d_out;
    float* ctx    = out;             // [B,H]
    float* scores = out + B_ * H_;   // [B,S]

    float* logits = (float*)d_ws;                 // B*S f32   (128 KB)
    float* t1     = logits + B_ * S_;             // B*H f32   (128 KB)
    u8*    W2f8   = (u8*)(t1 + B_ * H_);          // 1 MB, kt-tiled
    u8*    encF8  = W2f8 + (size_t)H_ * H_;       // 32 MB, kt-tiled

    prep_kernel<<<dim3(1024 + 1024 + 256), 256, 0, stream>>>(
        enc, W, hidden, bias, encF8, W2f8, t1, logits, ctx);
    energy_kernel<<<dim3(2048), 256, 0, stream>>>(W2f8, encF8, t1, v, logits);
    ctx_kernel<<<dim3(S_ / 32, B_), 256, 0, stream>>>(enc, logits, scores, ctx);
}

// Round 5
// 294.807 us; speedup vs baseline: 1.0546x; 1.0546x over previous
//
#include <hip/hip_runtime.h>
#include <hip/hip_bf16.h>
#include <math.h>

#define B_ 32
#define H_ 1024
#define S_ 1024

typedef float  f32x4_t  __attribute__((ext_vector_type(4)));
typedef float  f32x16_t __attribute__((ext_vector_type(16)));
typedef long long i64;
typedef i64 i64x2 __attribute__((ext_vector_type(2)));
typedef unsigned char u8;

// tanh via hw exp2 + rcp (~5 VALU inst, ~1e-6 abs err; saturates correctly)
__device__ __forceinline__ float tanh_fast(float x) {
    float e = __builtin_amdgcn_exp2f(x * 2.885390081777927f);  // e^(2x)
    return 1.f - 2.f * __builtin_amdgcn_rcpf(e + 1.f);
}

// fp8 k-permutation within a 32-k group: swap bits 3<->4 (involution).
__device__ __forceinline__ int kperm(int k) {
    return (k & ~24) | ((k & 8) << 1) | ((k & 16) >> 1);
}

// ---------------------------------------------------------------------------
// prep_kernel (round-13): role 0 reverted to the round-3 form — the best
// measured variant. Round-4's per-thread-line stores (8x16B at 32B stride
// across two passes) caused 1.75x WRITE amplification (34->59.7 MB,
// partial-line evictions) and were slower (84 vs 78us). Round-3 stores are
// 1KB contiguous per wave instruction (lane l covers (s=l>>1, khalf=l&1)),
// lines complete within one burst -> no amplification.
//
//  Role 0 [0,2048):    enc f32 -> encF8 e4m3 (kt-tiled, byte p of a chunk =
//                      source row kperm(p)). Thread <-> (4 consecutive s,
//                      khalf c); 16 float4 row-loads; 4x int4 stores.
//  Role 1 [2048,3072): W2f8[kt][h][32B] = e4m3(64 * W[h][H+k]) + zero logits
//  Role 2 [3072,3328): t1[b,h] = bias[h] + sum_k hidden[b,k]*W[h,k]
// ---------------------------------------------------------------------------
__global__ __launch_bounds__(256) void prep_kernel(
    const float* __restrict__ enc, const float* __restrict__ W,
    const float* __restrict__ hidden, const float* __restrict__ bias,
    u8* __restrict__ encF8, u8* __restrict__ W2f8,
    float* __restrict__ t1, float* __restrict__ logits,
    float* __restrict__ ctx)
{
    const int idx = blockIdx.x;
    const int tid = threadIdx.x;
    if (idx < 2048) {
        const int b  = idx >> 6;            // 0..31
        const int kt = (idx >> 1) & 31;     // 0..31
        const int s0 = (idx & 1) << 9;      // 0 or 512
        const int c  = tid & 1;             // khalf (16B half of 32B chunk)
        const int s  = s0 + ((tid >> 1) << 2);  // 4-aligned s, 128 per block

        const float* ebase = enc + ((size_t)b * S_ + (size_t)kt * 32) * H_ + s;
        f32x4_t f[16];
        #pragma unroll
        for (int i = 0; i < 16; ++i)
            f[i] = *reinterpret_cast<const f32x4_t*>(
                ebase + (size_t)kperm(c * 16 + i) * H_);

        u8* obase = encF8 + (size_t)b * 1048576 + (size_t)kt * 32768
                  + (size_t)s * 32 + c * 16;
        #pragma unroll
        for (int j = 0; j < 4; ++j) {
            int t0;
            int4 wv;
            t0   = __builtin_amdgcn_cvt_pk_fp8_f32(f[0][j],  f[1][j],  0,  false);
            wv.x = __builtin_amdgcn_cvt_pk_fp8_f32(f[2][j],  f[3][j],  t0, true);
            t0   = __builtin_amdgcn_cvt_pk_fp8_f32(f[4][j],  f[5][j],  0,  false);
            wv.y = __builtin_amdgcn_cvt_pk_fp8_f32(f[6][j],  f[7][j],  t0, true);
            t0   = __builtin_amdgcn_cvt_pk_fp8_f32(f[8][j],  f[9][j],  0,  false);
            wv.z = __builtin_amdgcn_cvt_pk_fp8_f32(f[10][j], f[11][j], t0, true);
            t0   = __builtin_amdgcn_cvt_pk_fp8_f32(f[12][j], f[13][j], 0,  false);
            wv.w = __builtin_amdgcn_cvt_pk_fp8_f32(f[14][j], f[15][j], t0, true);
            *reinterpret_cast<int4*>(obase + (size_t)j * 32) = wv;
        }
    } else if (idx < 3072) {
        int h = idx - 2048;  // one h row
        if (tid < 64) {      // zero logits (first 32768) then ctx (next 32768)
            int z = h * 64 + tid;
            if (z < B_ * S_) logits[z] = 0.f;
            else             ctx[z - B_ * S_] = 0.f;
        }
        int kt = tid >> 3;            // 0..31
        int q  = tid & 7;             // dest 4-byte word in 32B chunk
        int src = kperm(q * 4);       // contiguous 4 source floats
        float4 wv = *reinterpret_cast<const float4*>(
            W + (size_t)h * (2 * H_) + H_ + kt * 32 + src);
        int pw = __builtin_amdgcn_cvt_pk_fp8_f32(wv.x * 64.f, wv.y * 64.f, 0, false);
        pw     = __builtin_amdgcn_cvt_pk_fp8_f32(wv.z * 64.f, wv.w * 64.f, pw, true);
        *reinterpret_cast<int*>(W2f8 + (size_t)kt * 32768 + (size_t)h * 32 + q * 4) = pw;
    } else {
        int h    = (idx - 3072) * 4 + (tid >> 6);
        int lane = tid & 63;
        const float4* wp = reinterpret_cast<const float4*>(W + (size_t)h * (2 * H_));
        float4 w0 = wp[lane], w1 = wp[lane + 64], w2 = wp[lane + 128], w3 = wp[lane + 192];
        float bh = bias[h];
        for (int b = 0; b < B_; ++b) {
            const float4* hp = reinterpret_cast<const float4*>(hidden + b * H_);
            float4 h0 = hp[lane], h1 = hp[lane + 64], h2 = hp[lane + 128], h3 = hp[lane + 192];
            float a = w0.x*h0.x + w0.y*h0.y + w0.z*h0.z + w0.w*h0.w
                    + w1.x*h1.x + w1.y*h1.y + w1.z*h1.z + w1.w*h1.w
                    + w2.x*h2.x + w2.y*h2.y + w2.z*h2.z + w2.w*h2.w
                    + w3.x*h3.x + w3.y*h3.y + w3.z*h3.z + w3.w*h3.w;
            #pragma unroll
            for (int off = 1; off < 64; off <<= 1) a += __shfl_xor(a, off);
            if (lane == 0) t1[b * H_ + h] = a + bh;
        }
    }
}

// ---------------------------------------------------------------------------
// Energy GEMM v8 — FLAT (no LDS, no barriers), unchanged from round-0 best.
//   D[h,s] = sum_k W2[h,k]*enc[b,k,s]; logits[b,s] += sum_h v[h]*tanh(D+t1)
// ---------------------------------------------------------------------------
__global__ __launch_bounds__(256) void energy_kernel(
    const u8* __restrict__ W2f8, const u8* __restrict__ encF8,
    const float* __restrict__ t1, const float* __restrict__ v,
    float* __restrict__ logits)
{
    // XCD decode (round-6): all 8 h-tiles of one (s,b) group share id%8.
    const int id = blockIdx.x;
    const int q  = id >> 3, r = id & 7;
    const int ht = q & 7;
    const int g  = r + ((q >> 3) << 3);
    const int b  = g >> 3;
    const int h0 = ht * 128;
    const int s0 = (g & 7) * 128;

    const int tid   = threadIdx.x;
    const int lane  = tid & 63;
    const int wid   = tid >> 6;
    const int wm    = (wid & 1) * 64;
    const int wn    = (wid >> 1) * 64;
    const int l32   = lane & 31;
    const int khalf = lane >> 5;

    // per-lane fragment stream bases (advance 32768 B per kt)
    const u8* aP = W2f8 + (size_t)(h0 + wm + l32) * 32 + khalf * 16;
    const u8* bP = encF8 + (size_t)b * 1048576
                 + (size_t)(s0 + wn + l32) * 32 + khalf * 16;

    f32x16_t acc[2][2] = {};

    i64x2 ca0 = *reinterpret_cast<const i64x2*>(aP);
    i64x2 ca1 = *reinterpret_cast<const i64x2*>(aP + 1024);
    i64x2 cb0 = *reinterpret_cast<const i64x2*>(bP);
    i64x2 cb1 = *reinterpret_cast<const i64x2*>(bP + 1024);
    const u8* aN = aP + 32768;
    const u8* bN = bP + 32768;

    for (int kt = 0; kt < 31; ++kt) {
        i64x2 na0 = *reinterpret_cast<const i64x2*>(aN);
        i64x2 na1 = *reinterpret_cast<const i64x2*>(aN + 1024);
        i64x2 nb0 = *reinterpret_cast<const i64x2*>(bN);
        i64x2 nb1 = *reinterpret_cast<const i64x2*>(bN + 1024);
        aN += 32768; bN += 32768;

        acc[0][0] = __builtin_amdgcn_mfma_f32_32x32x16_fp8_fp8(ca0.x, cb0.x, acc[0][0], 0, 0, 0);
        acc[0][1] = __builtin_amdgcn_mfma_f32_32x32x16_fp8_fp8(ca0.x, cb1.x, acc[0][1], 0, 0, 0);
        acc[1][0] = __builtin_amdgcn_mfma_f32_32x32x16_fp8_fp8(ca1.x, cb0.x, acc[1][0], 0, 0, 0);
        acc[1][1] = __builtin_amdgcn_mfma_f32_32x32x16_fp8_fp8(ca1.x, cb1.x, acc[1][1], 0, 0, 0);
        acc[0][0] = __builtin_amdgcn_mfma_f32_32x32x16_fp8_fp8(ca0.y, cb0.y, acc[0][0], 0, 0, 0);
        acc[0][1] = __builtin_amdgcn_mfma_f32_32x32x16_fp8_fp8(ca0.y, cb1.y, acc[0][1], 0, 0, 0);
        acc[1][0] = __builtin_amdgcn_mfma_f32_32x32x16_fp8_fp8(ca1.y, cb0.y, acc[1][0], 0, 0, 0);
        acc[1][1] = __builtin_amdgcn_mfma_f32_32x32x16_fp8_fp8(ca1.y, cb1.y, acc[1][1], 0, 0, 0);

        ca0 = na0; ca1 = na1; cb0 = nb0; cb1 = nb1;
    }
    acc[0][0] = __builtin_amdgcn_mfma_f32_32x32x16_fp8_fp8(ca0.x, cb0.x, acc[0][0], 0, 0, 0);
    acc[0][1] = __builtin_amdgcn_mfma_f32_32x32x16_fp8_fp8(ca0.x, cb1.x, acc[0][1], 0, 0, 0);
    acc[1][0] = __builtin_amdgcn_mfma_f32_32x32x16_fp8_fp8(ca1.x, cb0.x, acc[1][0], 0, 0, 0);
    acc[1][1] = __builtin_amdgcn_mfma_f32_32x32x16_fp8_fp8(ca1.x, cb1.x, acc[1][1], 0, 0, 0);
    acc[0][0] = __builtin_amdgcn_mfma_f32_32x32x16_fp8_fp8(ca0.y, cb0.y, acc[0][0], 0, 0, 0);
    acc[0][1] = __builtin_amdgcn_mfma_f32_32x32x16_fp8_fp8(ca0.y, cb1.y, acc[0][1], 0, 0, 0);
    acc[1][0] = __builtin_amdgcn_mfma_f32_32x32x16_fp8_fp8(ca1.y, cb0.y, acc[1][0], 0, 0, 0);
    acc[1][1] = __builtin_amdgcn_mfma_f32_32x32x16_fp8_fp8(ca1.y, cb1.y, acc[1][1], 0, 0, 0);

    // epilogue: 32x32 C/D: col = lane&31, row = (r&3)+8*(r>>2)+4*(lane>>5)
    float pn0 = 0.f, pn1 = 0.f;
    #pragma unroll
    for (int mt = 0; mt < 2; ++mt)
        #pragma unroll
        for (int rr = 0; rr < 16; ++rr) {
            int rowm = wm + mt * 32 + (rr & 3) + 8 * (rr >> 2) + 4 * khalf;
            int h = h0 + rowm;
            float tv = t1[b * H_ + h];
            float vv = v[h];
            pn0 += vv * tanh_fast(acc[mt][0][rr] * 0.015625f + tv);
            pn1 += vv * tanh_fast(acc[mt][1][rr] * 0.015625f + tv);
        }
    pn0 += __shfl_xor(pn0, 32);
    pn1 += __shfl_xor(pn1, 32);
    if (lane < 32) {
        atomicAdd(&logits[(size_t)b * S_ + s0 + wn + l32], pn0);
        atomicAdd(&logits[(size_t)b * S_ + s0 + wn + 32 + l32], pn1);
    }
}

// ---------------------------------------------------------------------------
// Fused softmax + context (round-13): grid (32 s-chunks, B) = 1024 blocks.
// CHANGE: the 4 scalar device-scope atomicAdds per thread (1M total onto a
// 128KB buffer, 32-way contention per word) are replaced by plain coalesced
// float4 stores into per-(b,chunk) partial slabs ctxp[b][chunk][h]; a tiny
// reduce kernel folds the 32 partials. Removes all atomic serialization from
// the main streaming loop.
// ---------------------------------------------------------------------------
__global__ __launch_bounds__(256) void ctx_kernel(
    const float* __restrict__ enc, const float* __restrict__ logits,
    float* __restrict__ scores, float* __restrict__ ctxp)
{
    __shared__ float sc[1024];
    __shared__ float red[8];
    const int b    = blockIdx.y;
    const int s0   = blockIdx.x * 32;
    const int tid  = threadIdx.x;
    const int lane = tid & 63;
    const int w    = tid >> 6;

    float4 lg = *reinterpret_cast<const float4*>(logits + (size_t)b * S_ + tid * 4);
    float mx = fmaxf(fmaxf(lg.x, lg.y), fmaxf(lg.z, lg.w));
    #pragma unroll
    for (int off = 1; off < 64; off <<= 1) mx = fmaxf(mx, __shfl_xor(mx, off));
    if (lane == 0) red[w] = mx;
    __syncthreads();
    mx = fmaxf(fmaxf(red[0], red[1]), fmaxf(red[2], red[3]));
    const float L2E = 1.44269504088896f;
    float e0 = __builtin_amdgcn_exp2f((lg.x - mx) * L2E);
    float e1 = __builtin_amdgcn_exp2f((lg.y - mx) * L2E);
    float e2 = __builtin_amdgcn_exp2f((lg.z - mx) * L2E);
    float e3 = __builtin_amdgcn_exp2f((lg.w - mx) * L2E);
    float s = e0 + e1 + e2 + e3;
    #pragma unroll
    for (int off = 1; off < 64; off <<= 1) s += __shfl_xor(s, off);
    if (lane == 0) red[4 + w] = s;
    __syncthreads();
    float inv = 1.f / (red[4] + red[5] + red[6] + red[7]);
    float4 sv = { e0 * inv, e1 * inv, e2 * inv, e3 * inv };
    *reinterpret_cast<float4*>(&sc[tid * 4]) = sv;
    if (blockIdx.x == 0)
        *reinterpret_cast<float4*>(scores + (size_t)b * S_ + tid * 4) = sv;
    __syncthreads();

    f32x4_t accv = {0.f, 0.f, 0.f, 0.f};
    const float* ebase = enc + ((size_t)b * S_ + s0) * H_ + tid * 4;
    #pragma unroll 16
    for (int si = 0; si < 32; ++si) {
        float wgt = sc[s0 + si];
        float4 ev = *reinterpret_cast<const float4*>(ebase + (size_t)si * H_);
        accv[0] += wgt * ev.x;
        accv[1] += wgt * ev.y;
        accv[2] += wgt * ev.z;
        accv[3] += wgt * ev.w;
    }
    // coalesced partial store: ctxp[b][chunk][h], no contention
    *reinterpret_cast<f32x4_t*>(
        ctxp + ((size_t)b * 32 + blockIdx.x) * H_ + tid * 4) = accv;
}

// ---------------------------------------------------------------------------
// reduce_kernel: ctx[b][h] = sum over 32 chunks of ctxp[b][chunk][h].
// 32 blocks (one per b), 256 threads; per thread 32 float4 loads (each wave
// instruction reads 4KB contiguous), sum, one float4 store. ~4MB from L2/L3.
// ---------------------------------------------------------------------------
__global__ __launch_bounds__(256) void reduce_kernel(
    const float* __restrict__ ctxp, float* __restrict__ ctx)
{
    const int b   = blockIdx.x;
    const int tid = threadIdx.x;
    f32x4_t a = {0.f, 0.f, 0.f, 0.f};
    const float* base = ctxp + (size_t)b * 32 * H_ + tid * 4;
    #pragma unroll 8
    for (int c = 0; c < 32; ++c) {
        f32x4_t p = *reinterpret_cast<const f32x4_t*>(base + (size_t)c * H_);
        a[0] += p[0]; a[1] += p[1]; a[2] += p[2]; a[3] += p[3];
    }
    *reinterpret_cast<f32x4_t*>(ctx + (size_t)b * H_ + tid * 4) = a;
}

// ---------------------------------------------------------------------------
extern "C" void kernel_launch(void* const* d_in, const int* in_sizes, int n_in,
                              void* d_out, int out_size, void* d_ws, size_t ws_size,
                              hipStream_t stream)
{
    (void)in_sizes; (void)n_in; (void)out_size; (void)ws_size;
    const float* hidden = (const float*)d_in[0];
    const float* enc    = (const float*)d_in[1];
    const float* W      = (const float*)d_in[2];
    const float* bias   = (const float*)d_in[3];
    const float* v      = (const float*)d_in[4];

    float* out    = (float*)d_out;
    float* ctx    = out;             // [B,H]
    float* scores = out + B_ * H_;   // [B,S]

    float* logits = (float*)d_ws;                 // B*S f32   (128 KB)
    float* t1     = logits + B_ * S_;             // B*H f32   (128 KB)
    u8*    W2f8   = (u8*)(t1 + B_ * H_);          // 1 MB, kt-tiled
    u8*    encF8  = W2f8 + (size_t)H_ * H_;       // 32 MB, kt-tiled
    float* ctxp   = (float*)(encF8 + (size_t)B_ * S_ * H_);  // 4 MB partials

    prep_kernel<<<dim3(2048 + 1024 + 256), 256, 0, stream>>>(
        enc, W, hidden, bias, encF8, W2f8, t1, logits, ctx);
    energy_kernel<<<dim3(2048), 256, 0, stream>>>(W2f8, encF8, t1, v, logits);
    ctx_kernel<<<dim3(S_ / 32, B_), 256, 0, stream>>>(enc, logits, scores, ctxp);
    reduce_kernel<<<dim3(B_), 256, 0, stream>>>(ctxp, ctx);
}